// Round 7
// baseline (667.285 us; speedup 1.0000x reference)
//
#include <hip/hip_runtime.h>
#include <hip/hip_bf16.h>

#define NPTS 8192
#define DIM  512
#define NHEAD 8
#define HDIM 64

typedef short bf16x8 __attribute__((ext_vector_type(8)));   // 8 bf16 = 4 VGPRs
typedef float f32x4  __attribute__((ext_vector_type(4)));   // MFMA C/D

#define GLOBAL_AS __attribute__((address_space(1)))
#define LDS_AS    __attribute__((address_space(3)))

#if __has_builtin(__builtin_amdgcn_exp2f)
#define EXP2F(x) __builtin_amdgcn_exp2f(x)
#else
#define EXP2F(x) __expf((x) * 0.6931471805599453f)
#endif

// fp32 -> bf16 round-nearest-even
__device__ __forceinline__ unsigned short f2bf(float f) {
    union { float f; unsigned int u; } v; v.f = f;
    unsigned int r = v.u + 0x7FFFu + ((v.u >> 16) & 1u);
    return (unsigned short)(r >> 16);
}
__device__ __forceinline__ float bf2f(unsigned short u) {
    union { unsigned int i; float f; } v; v.i = ((unsigned int)u) << 16;
    return v.f;
}

// ---------------------------------------------------------------------------
// Prep 1: x fp32 -> bf16
// ---------------------------------------------------------------------------
__global__ __launch_bounds__(256) void cvt_x_kernel(
    const float* __restrict__ in, unsigned short* __restrict__ outp)
{
    int gid = blockIdx.x * 256 + threadIdx.x;   // over N*DIM/8
    float4 a = ((const float4*)in)[gid * 2];
    float4 b = ((const float4*)in)[gid * 2 + 1];
    ushort4 ua, ub;
    ua.x = f2bf(a.x); ua.y = f2bf(a.y); ua.z = f2bf(a.z); ua.w = f2bf(a.w);
    ub.x = f2bf(b.x); ub.y = f2bf(b.y); ub.z = f2bf(b.z); ub.w = f2bf(b.w);
    ((ushort4*)outp)[gid * 2]     = ua;
    ((ushort4*)outp)[gid * 2 + 1] = ub;
}

// ---------------------------------------------------------------------------
// Prep 2: Wq/Wk/Wv [h][512][64] fp32 -> wtq [zh][64][512] bf16 (transposed)
// ---------------------------------------------------------------------------
__global__ __launch_bounds__(256) void tr_w_kernel(
    const float* __restrict__ Wq, const float* __restrict__ Wk,
    const float* __restrict__ Wv, unsigned short* __restrict__ wtq)
{
    int zh = blockIdx.z, z = zh >> 3, h = zh & 7;
    const float* src = (z == 0 ? Wq : z == 1 ? Wk : Wv) + (size_t)h * DIM * HDIM;
    unsigned short* dst = wtq + (size_t)zh * HDIM * DIM;
    int k0 = blockIdx.x * 64;
    __shared__ float tile[64][65];
    int t = threadIdx.x, c = t & 63, r = t >> 6;
    #pragma unroll
    for (int i = 0; i < 16; ++i)
        tile[r + 4 * i][c] = src[(size_t)(k0 + r + 4 * i) * HDIM + c];
    __syncthreads();
    #pragma unroll
    for (int i = 0; i < 16; ++i)
        dst[(size_t)(r + 4 * i) * DIM + k0 + c] = f2bf(tile[c][r + 4 * i]);
}

// ---------------------------------------------------------------------------
// Prep 3: Wo [512][512] fp32 -> wot [512][512] bf16 transposed ([e_out][k])
// ---------------------------------------------------------------------------
__global__ __launch_bounds__(256) void tr_wo_kernel(
    const float* __restrict__ Wo, unsigned short* __restrict__ wot)
{
    int k0 = blockIdx.x * 64, e0 = blockIdx.y * 64;
    __shared__ float tile[64][65];
    int t = threadIdx.x, c = t & 63, r = t >> 6;
    #pragma unroll
    for (int i = 0; i < 16; ++i)
        tile[r + 4 * i][c] = Wo[(size_t)(k0 + r + 4 * i) * DIM + e0 + c];
    __syncthreads();
    #pragma unroll
    for (int i = 0; i < 16; ++i)
        wot[(size_t)(e0 + r + 4 * i) * DIM + k0 + c] = f2bf(tile[c][r + 4 * i]);
}

// ---------------------------------------------------------------------------
// QKV projection, bf16 MFMA, direct-global frags.
//   z=0: q_bf[h][n][e]  (scale*log2e folded)   z=1: k_bf[h][n][e]
//   z=2: vt_bf[h][e][n] = V^T, PLAIN order (kappa removed), packed stores
// ---------------------------------------------------------------------------
__global__ __launch_bounds__(256) void qkv_mfma_kernel(
    const unsigned short* __restrict__ xbf,   // [N][512] bf16
    const unsigned short* __restrict__ wtq,   // [24][64][512] bf16
    const float* __restrict__ bq, const float* __restrict__ bk,
    const float* __restrict__ bv,
    unsigned short* __restrict__ q_bf, unsigned short* __restrict__ k_bf,
    unsigned short* __restrict__ vt_bf)
{
    const int zh = blockIdx.y, z = zh >> 3, h = zh & 7;
    const unsigned short* W = wtq + (size_t)zh * HDIM * DIM;
    const float* b = (z == 0 ? bq : z == 1 ? bk : bv) + h * HDIM;
    const int t = threadIdx.x, w = t >> 6, lane = t & 63;
    const int l15 = lane & 15, quad = lane >> 4;
    const int r0 = blockIdx.x * 128 + w * 32;

    f32x4 O[2][4];
    #pragma unroll
    for (int mt = 0; mt < 2; ++mt)
        #pragma unroll
        for (int tn = 0; tn < 4; ++tn) O[mt][tn] = (f32x4){0.f, 0.f, 0.f, 0.f};

    for (int k0 = 0; k0 < DIM; k0 += 64) {
        bf16x8 af[2][2], bf[4][2];
        #pragma unroll
        for (int mt = 0; mt < 2; ++mt)
            #pragma unroll
            for (int kc = 0; kc < 2; ++kc)
                af[mt][kc] = *(const bf16x8*)
                    &xbf[(size_t)(r0 + 16 * mt + l15) * DIM + k0 + quad * 8 + 32 * kc];
        #pragma unroll
        for (int tn = 0; tn < 4; ++tn)
            #pragma unroll
            for (int kc = 0; kc < 2; ++kc)
                bf[tn][kc] = *(const bf16x8*)
                    &W[(size_t)(l15 + 16 * tn) * DIM + k0 + quad * 8 + 32 * kc];
        #pragma unroll
        for (int mt = 0; mt < 2; ++mt)
            #pragma unroll
            for (int tn = 0; tn < 4; ++tn) {
                O[mt][tn] = __builtin_amdgcn_mfma_f32_16x16x32_bf16(
                    af[mt][0], bf[tn][0], O[mt][tn], 0, 0, 0);
                O[mt][tn] = __builtin_amdgcn_mfma_f32_16x16x32_bf16(
                    af[mt][1], bf[tn][1], O[mt][tn], 0, 0, 0);
            }
    }

    if (z < 2) {
        unsigned short* outp = (z == 0 ? q_bf : k_bf) + (size_t)h * NPTS * HDIM;
        const float sc = (z == 0) ? 0.18033688011112042f : 1.0f;  // 0.125*log2e | 1
        #pragma unroll
        for (int mt = 0; mt < 2; ++mt)
            #pragma unroll
            for (int tn = 0; tn < 4; ++tn) {
                int e = l15 + 16 * tn;
                float be = b[e];
                #pragma unroll
                for (int r = 0; r < 4; ++r) {
                    int n = r0 + 16 * mt + quad * 4 + r;
                    outp[(size_t)n * HDIM + e] = f2bf((O[mt][tn][r] + be) * sc);
                }
            }
    } else {
        unsigned short* vt = vt_bf + (size_t)h * HDIM * NPTS;
        #pragma unroll
        for (int mt = 0; mt < 2; ++mt)
            #pragma unroll
            for (int tn = 0; tn < 4; ++tn) {
                int e = l15 + 16 * tn;
                float be = b[e];
                int n0 = r0 + 16 * mt + quad * 4;
                ushort4 pk;
                pk.x = f2bf(O[mt][tn][0] + be);
                pk.y = f2bf(O[mt][tn][1] + be);
                pk.z = f2bf(O[mt][tn][2] + be);
                pk.w = f2bf(O[mt][tn][3] + be);
                *(ushort4*)&vt[(size_t)e * NPTS + n0] = pk;
            }
    }
}

// ---------------------------------------------------------------------------
// MFMA flash attention, R7: transpose trick. Compute S^T = mfma(kf, qf)
// (A/B frag register layouts are identical, so operand swap is free). S^T's
// C-layout (row=quad*4+r = key, col=l15 = qrow) IS the B-frag layout for the
// PV MFMA under the consistent k-permutation sigma(quad,j) =
// {j<4: quad*4+j, j>=4: 16+quad*4+(j-4)} applied to both P^T (B) and V (A).
// => P never leaves registers: no Plds, no LDS round-trip, no kappa.
// K staged double-buffered via global_load_lds (one barrier/iter, R6);
// V A-frags direct from global V^T; max-free softmax; k-split 2 + reduce.
// ---------------------------------------------------------------------------
__global__ __launch_bounds__(256) void attn_kernel(
    const unsigned short* __restrict__ qg,   // [H][N][64] bf16, pre-scaled
    const unsigned short* __restrict__ kg,   // [H][N][64] bf16
    const unsigned short* __restrict__ vtg,  // [H][64][N] bf16, plain V^T
    unsigned short* __restrict__ opart,      // [2][N][DIM] bf16 unnormalized
    float* __restrict__ lpart)               // [2][H][N] fp32
{
    const int h  = blockIdx.y;
    const int ks = blockIdx.z;
    const int q0 = blockIdx.x * 128;
    const int kbase = ks * (NPTS / 2);
    const unsigned short* Q  = qg  + (size_t)h * NPTS * HDIM;
    const unsigned short* K  = kg  + (size_t)h * NPTS * HDIM;
    const unsigned short* Vt = vtg + (size_t)h * HDIM * NPTS;
    unsigned short* op = opart + (size_t)ks * NPTS * DIM;
    float* lp = lpart + (size_t)(ks * NHEAD + h) * NPTS;

    __shared__ __align__(16) unsigned short Klds[2][64 * 64];  // 16 KB total

    const int t    = threadIdx.x;
    const int w    = t >> 6;
    const int lane = t & 63;
    const int l15  = lane & 15;
    const int quad = lane >> 4;

    const int koff0 = l15 * 64 + (quad ^ (l15 & 7)) * 8;
    const int koff1 = koff0 ^ 32;

    const int srow   = lane >> 3;
    const int schunk = (lane & 7) ^ srow;

    // Q B-frags (same register content as the old A-frags)
    bf16x8 qf[2][2];
    #pragma unroll
    for (int m = 0; m < 2; ++m)
        #pragma unroll
        for (int kc = 0; kc < 2; ++kc)
            qf[m][kc] = *(const bf16x8*)
                &Q[(size_t)(q0 + 32 * w + 16 * m + l15) * HDIM + quad * 8 + 32 * kc];

    // O^T accumulators [te][m]: C-layout row=quad*4+r -> e, col=l15 -> qrow
    f32x4 OT[4][2];
    float lsum[2] = {0.f, 0.f};
    #pragma unroll
    for (int te = 0; te < 4; ++te)
        #pragma unroll
        for (int m = 0; m < 2; ++m) OT[te][m] = (f32x4){0.f, 0.f, 0.f, 0.f};

    auto stage = [&](int kt, int buf) {
        #pragma unroll
        for (int i = 0; i < 2; ++i) {
            int rb = 16 * w + 8 * i;
            __builtin_amdgcn_global_load_lds(
                (const GLOBAL_AS void*)&K[(size_t)(kbase + kt + rb + srow) * HDIM
                                          + schunk * 8],
                (LDS_AS void*)&Klds[buf][rb * 64], 16, 0, 0);
        }
    };

    stage(0, 0);
    __syncthreads();
    int buf = 0;

    for (int kt = 0; kt < NPTS / 2; kt += 64) {
        if (kt + 64 < NPTS / 2) stage(kt + 64, buf ^ 1);

        // V A-frags under sigma: vf[te][kb] j<4 <- Vt[e][kb*32+quad*4+j],
        // j>=4 <- Vt[e][kb*32+16+quad*4+(j-4)]
        bf16x8 vf[4][2];
        #pragma unroll
        for (int te = 0; te < 4; ++te)
            #pragma unroll
            for (int kb = 0; kb < 2; ++kb) {
                const unsigned short* vp =
                    &Vt[(size_t)(16 * te + l15) * NPTS + kbase + kt + kb * 32 + quad * 4];
                uint2 lo = *(const uint2*)vp;
                uint2 hi = *(const uint2*)(vp + 16);
                union { uint4 u; bf16x8 v; } uu;
                uu.u = (uint4){lo.x, lo.y, hi.x, hi.y};
                vf[te][kb] = uu.v;
            }

        // K A-frags from LDS (same reads as before)
        bf16x8 kf[4][2];
        #pragma unroll
        for (int kn = 0; kn < 4; ++kn) {
            kf[kn][0] = *(const bf16x8*)&Klds[buf][1024 * kn + koff0];
            kf[kn][1] = *(const bf16x8*)&Klds[buf][1024 * kn + koff1];
        }

        // S^T = K Q^T : st[kn][m], row=key(quad*4+r), col=qrow(l15)
        f32x4 st[4][2];
        #pragma unroll
        for (int kn = 0; kn < 4; ++kn)
            #pragma unroll
            for (int m = 0; m < 2; ++m) st[kn][m] = (f32x4){0.f, 0.f, 0.f, 0.f};
        #pragma unroll
        for (int kn = 0; kn < 4; ++kn)
            #pragma unroll
            for (int m = 0; m < 2; ++m) {
                st[kn][m] = __builtin_amdgcn_mfma_f32_16x16x32_bf16(
                    kf[kn][0], qf[m][0], st[kn][m], 0, 0, 0);
                st[kn][m] = __builtin_amdgcn_mfma_f32_16x16x32_bf16(
                    kf[kn][1], qf[m][1], st[kn][m], 0, 0, 0);
            }

        // max-free softmax in registers: pt[kb][m] = bf16 exp2(S^T), B-frag
        bf16x8 pt[2][2];
        #pragma unroll
        for (int kb = 0; kb < 2; ++kb)
            #pragma unroll
            for (int m = 0; m < 2; ++m) {
                float a0 = EXP2F(st[2 * kb + 0][m][0]);
                float a1 = EXP2F(st[2 * kb + 0][m][1]);
                float a2 = EXP2F(st[2 * kb + 0][m][2]);
                float a3 = EXP2F(st[2 * kb + 0][m][3]);
                float b0 = EXP2F(st[2 * kb + 1][m][0]);
                float b1 = EXP2F(st[2 * kb + 1][m][1]);
                float b2 = EXP2F(st[2 * kb + 1][m][2]);
                float b3 = EXP2F(st[2 * kb + 1][m][3]);
                lsum[m] += ((a0 + a1) + (a2 + a3)) + ((b0 + b1) + (b2 + b3));
                union { uint4 u; bf16x8 v; } uu;
                uu.u.x = (unsigned int)f2bf(a0) | ((unsigned int)f2bf(a1) << 16);
                uu.u.y = (unsigned int)f2bf(a2) | ((unsigned int)f2bf(a3) << 16);
                uu.u.z = (unsigned int)f2bf(b0) | ((unsigned int)f2bf(b1) << 16);
                uu.u.w = (unsigned int)f2bf(b2) | ((unsigned int)f2bf(b3) << 16);
                pt[kb][m] = uu.v;
            }

        // O^T += V^T P^T  (pure register path)
        #pragma unroll
        for (int te = 0; te < 4; ++te)
            #pragma unroll
            for (int m = 0; m < 2; ++m) {
                OT[te][m] = __builtin_amdgcn_mfma_f32_16x16x32_bf16(
                    vf[te][0], pt[0][m], OT[te][m], 0, 0, 0);
                OT[te][m] = __builtin_amdgcn_mfma_f32_16x16x32_bf16(
                    vf[te][1], pt[1][m], OT[te][m], 0, 0, 0);
            }

        __syncthreads();   // Klds[buf] reads done; next stage visible
        buf ^= 1;
    }

    // epilogue: l reduced across quads (cols replicate over quad after shfl);
    // write unnormalized O^T as packed ushort4 (e runs along regs)
    #pragma unroll
    for (int m = 0; m < 2; ++m) {
        float l = lsum[m];
        l += __shfl_xor(l, 16);
        l += __shfl_xor(l, 32);
        int n = q0 + 32 * w + 16 * m + l15;
        if (quad == 0) lp[n] = l;
        #pragma unroll
        for (int te = 0; te < 4; ++te) {
            ushort4 pk;
            pk.x = f2bf(OT[te][m][0]);
            pk.y = f2bf(OT[te][m][1]);
            pk.z = f2bf(OT[te][m][2]);
            pk.w = f2bf(OT[te][m][3]);
            *(ushort4*)&op[(size_t)n * DIM + h * HDIM + 16 * te + quad * 4] = pk;
        }
    }
}

// ---------------------------------------------------------------------------
// Merge k-split partials: op0 <- bf16((op0 + op1) / (l0 + l1))  in place.
// ---------------------------------------------------------------------------
__global__ __launch_bounds__(256) void reduce_kernel(
    unsigned short* __restrict__ op0, const unsigned short* __restrict__ op1,
    const float* __restrict__ l0, const float* __restrict__ l1)
{
    int gid = blockIdx.x * 256 + threadIdx.x;   // over N*DIM/4
    int n  = gid >> 7;
    int c4 = gid & 127;
    int h  = c4 >> 4;
    float inv = 1.0f / (l0[h * NPTS + n] + l1[h * NPTS + n]);
    ushort4 a = *(const ushort4*)&op0[(size_t)gid * 4];
    ushort4 b = *(const ushort4*)&op1[(size_t)gid * 4];
    ushort4 o;
    o.x = f2bf((bf2f(a.x) + bf2f(b.x)) * inv);
    o.y = f2bf((bf2f(a.y) + bf2f(b.y)) * inv);
    o.z = f2bf((bf2f(a.z) + bf2f(b.z)) * inv);
    o.w = f2bf((bf2f(a.w) + bf2f(b.w)) * inv);
    *(ushort4*)&op0[(size_t)gid * 4] = o;
}

// ---------------------------------------------------------------------------
// Output projection, bf16 MFMA, direct-global frags.
// ---------------------------------------------------------------------------
__global__ __launch_bounds__(256) void out_mfma_kernel(
    const unsigned short* __restrict__ cc,    // [N][512] bf16 normalized heads
    const unsigned short* __restrict__ wot,   // [512][512] bf16 [e_out][k]
    const float* __restrict__ bo, const float* __restrict__ x,
    float* __restrict__ outp)
{
    const int t = threadIdx.x, w = t >> 6, lane = t & 63;
    const int l15 = lane & 15, quad = lane >> 4;
    const int r0 = blockIdx.x * 128 + w * 32;
    const int c0 = blockIdx.y * 64;

    f32x4 O[2][4];
    #pragma unroll
    for (int mt = 0; mt < 2; ++mt)
        #pragma unroll
        for (int tn = 0; tn < 4; ++tn) O[mt][tn] = (f32x4){0.f, 0.f, 0.f, 0.f};

    for (int k0 = 0; k0 < DIM; k0 += 64) {
        bf16x8 af[2][2], bf[4][2];
        #pragma unroll
        for (int mt = 0; mt < 2; ++mt)
            #pragma unroll
            for (int kc = 0; kc < 2; ++kc)
                af[mt][kc] = *(const bf16x8*)
                    &cc[(size_t)(r0 + 16 * mt + l15) * DIM + k0 + quad * 8 + 32 * kc];
        #pragma unroll
        for (int tn = 0; tn < 4; ++tn)
            #pragma unroll
            for (int kc = 0; kc < 2; ++kc)
                bf[tn][kc] = *(const bf16x8*)
                    &wot[(size_t)(c0 + l15 + 16 * tn) * DIM + k0 + quad * 8 + 32 * kc];
        #pragma unroll
        for (int mt = 0; mt < 2; ++mt)
            #pragma unroll
            for (int tn = 0; tn < 4; ++tn) {
                O[mt][tn] = __builtin_amdgcn_mfma_f32_16x16x32_bf16(
                    af[mt][0], bf[tn][0], O[mt][tn], 0, 0, 0);
                O[mt][tn] = __builtin_amdgcn_mfma_f32_16x16x32_bf16(
                    af[mt][1], bf[tn][1], O[mt][tn], 0, 0, 0);
            }
    }

    #pragma unroll
    for (int mt = 0; mt < 2; ++mt)
        #pragma unroll
        for (int tn = 0; tn < 4; ++tn) {
            int e = c0 + l15 + 16 * tn;
            float be = bo[e];
            #pragma unroll
            for (int r = 0; r < 4; ++r) {
                int n = r0 + 16 * mt + quad * 4 + r;
                outp[(size_t)n * DIM + e] = O[mt][tn][r] + be + x[(size_t)n * DIM + e];
            }
        }
}

extern "C" void kernel_launch(void* const* d_in, const int* in_sizes, int n_in,
                              void* d_out, int out_size, void* d_ws, size_t ws_size,
                              hipStream_t stream) {
    const float* x  = (const float*)d_in[0];
    const float* Wq = (const float*)d_in[1];
    const float* bq = (const float*)d_in[2];
    const float* Wk = (const float*)d_in[3];
    const float* bk = (const float*)d_in[4];
    const float* Wv = (const float*)d_in[5];
    const float* bv = (const float*)d_in[6];
    const float* Wo = (const float*)d_in[7];
    const float* bo = (const float*)d_in[8];
    float* out = (float*)d_out;

    const size_t per = (size_t)NHEAD * NPTS * HDIM;            // 4M elems
    unsigned short* xbf   = (unsigned short*)d_ws;             //  8 MB
    unsigned short* wtq   = xbf + (size_t)NPTS * DIM;          //  1.5 MB
    unsigned short* wot   = wtq + (size_t)24 * HDIM * DIM;     //  0.5 MB
    unsigned short* q_bf  = wot + (size_t)DIM * DIM;           //  8 MB
    unsigned short* k_bf  = q_bf + per;                        //  8 MB
    unsigned short* vt_bf = k_bf + per;                        //  8 MB
    unsigned short* op0   = vt_bf + per;                       //  8 MB
    unsigned short* op1   = op0 + (size_t)NPTS * DIM;          //  8 MB
    float*          lpart = (float*)(op1 + (size_t)NPTS * DIM); // 512 KB
    // total ws: ~50.5 MB

    cvt_x_kernel<<<dim3(NPTS * DIM / 8 / 256), 256, 0, stream>>>(x, xbf);
    tr_w_kernel<<<dim3(8, 1, 24), 256, 0, stream>>>(Wq, Wk, Wv, wtq);
    tr_wo_kernel<<<dim3(8, 8), 256, 0, stream>>>(Wo, wot);
    qkv_mfma_kernel<<<dim3(NPTS / 128, 24), 256, 0, stream>>>(
        xbf, wtq, bq, bk, bv, q_bf, k_bf, vt_bf);
    attn_kernel<<<dim3(NPTS / 128, NHEAD, 2), 256, 0, stream>>>(
        q_bf, k_bf, vt_bf, op0, lpart);
    reduce_kernel<<<dim3(NPTS * DIM / 4 / 256), 256, 0, stream>>>(
        op0, op1, lpart, lpart + (size_t)NHEAD * NPTS);
    out_mfma_kernel<<<dim3(NPTS / 128, DIM / 64), 256, 0, stream>>>(
        op0, wot, bo, x, out);
}

// Round 8
// 448.491 us; speedup vs baseline: 1.4878x; 1.4878x over previous
//
#include <hip/hip_runtime.h>
#include <hip/hip_bf16.h>

#define NPTS 8192
#define DIM  512
#define NHEAD 8
#define HDIM 64

typedef short bf16x8 __attribute__((ext_vector_type(8)));   // 8 bf16 = 4 VGPRs
typedef float f32x4  __attribute__((ext_vector_type(4)));   // MFMA C/D

#define GLOBAL_AS __attribute__((address_space(1)))
#define LDS_AS    __attribute__((address_space(3)))

#if __has_builtin(__builtin_amdgcn_exp2f)
#define EXP2F(x) __builtin_amdgcn_exp2f(x)
#else
#define EXP2F(x) __expf((x) * 0.6931471805599453f)
#endif

// fp32 -> bf16 round-nearest-even (scalar)
__device__ __forceinline__ unsigned short f2bf(float f) {
    union { float f; unsigned int u; } v; v.f = f;
    unsigned int r = v.u + 0x7FFFu + ((v.u >> 16) & 1u);
    return (unsigned short)(r >> 16);
}
__device__ __forceinline__ float bf2f(unsigned short u) {
    union { unsigned int i; float f; } v; v.i = ((unsigned int)u) << 16;
    return v.f;
}
// packed 2x f32 -> bf16 pair (v_cvt_pk_bf16_f32 on gfx950)
__device__ __forceinline__ unsigned int pk2bf(float a, float b) {
    __hip_bfloat162 h = __float22bfloat162_rn(float2{a, b});
    union { __hip_bfloat162 h; unsigned int u; } v; v.h = h;
    return v.u;
}

// ---------------------------------------------------------------------------
// Prep 1: x fp32 -> bf16
// ---------------------------------------------------------------------------
__global__ __launch_bounds__(256) void cvt_x_kernel(
    const float* __restrict__ in, unsigned short* __restrict__ outp)
{
    int gid = blockIdx.x * 256 + threadIdx.x;   // over N*DIM/8
    float4 a = ((const float4*)in)[gid * 2];
    float4 b = ((const float4*)in)[gid * 2 + 1];
    uint4 u;
    u.x = pk2bf(a.x, a.y); u.y = pk2bf(a.z, a.w);
    u.z = pk2bf(b.x, b.y); u.w = pk2bf(b.z, b.w);
    ((uint4*)outp)[gid] = u;
}

// ---------------------------------------------------------------------------
// Prep 2: Wq/Wk/Wv [h][512][64] fp32 -> wtq [zh][64][512] bf16 (transposed)
// ---------------------------------------------------------------------------
__global__ __launch_bounds__(256) void tr_w_kernel(
    const float* __restrict__ Wq, const float* __restrict__ Wk,
    const float* __restrict__ Wv, unsigned short* __restrict__ wtq)
{
    int zh = blockIdx.z, z = zh >> 3, h = zh & 7;
    const float* src = (z == 0 ? Wq : z == 1 ? Wk : Wv) + (size_t)h * DIM * HDIM;
    unsigned short* dst = wtq + (size_t)zh * HDIM * DIM;
    int k0 = blockIdx.x * 64;
    __shared__ float tile[64][65];
    int t = threadIdx.x, c = t & 63, r = t >> 6;
    #pragma unroll
    for (int i = 0; i < 16; ++i)
        tile[r + 4 * i][c] = src[(size_t)(k0 + r + 4 * i) * HDIM + c];
    __syncthreads();
    #pragma unroll
    for (int i = 0; i < 16; ++i)
        dst[(size_t)(r + 4 * i) * DIM + k0 + c] = f2bf(tile[c][r + 4 * i]);
}

// ---------------------------------------------------------------------------
// Prep 3: Wo [512][512] fp32 -> wot [512][512] bf16 transposed ([e_out][k])
// ---------------------------------------------------------------------------
__global__ __launch_bounds__(256) void tr_wo_kernel(
    const float* __restrict__ Wo, unsigned short* __restrict__ wot)
{
    int k0 = blockIdx.x * 64, e0 = blockIdx.y * 64;
    __shared__ float tile[64][65];
    int t = threadIdx.x, c = t & 63, r = t >> 6;
    #pragma unroll
    for (int i = 0; i < 16; ++i)
        tile[r + 4 * i][c] = Wo[(size_t)(k0 + r + 4 * i) * DIM + e0 + c];
    __syncthreads();
    #pragma unroll
    for (int i = 0; i < 16; ++i)
        wot[(size_t)(e0 + r + 4 * i) * DIM + k0 + c] = f2bf(tile[c][r + 4 * i]);
}

// ---------------------------------------------------------------------------
// QKV projection, bf16 MFMA, direct-global frags.
//   z=0: q_bf[h][n][e]  (scale*log2e folded)   z=1: k_bf[h][n][e]
//   z=2: vtp[h][e][pi(n)] = V^T with the PV sigma-permutation pre-applied
//        within each 32-key block: pos = 32*blk + quad*8 + hi*4 + j  holds
//        key = 32*blk + 16*hi + quad*4 + j.  In C-layout terms the wave's
//        rows n = base + 16*mt + quad*4 + r store at base + quad*8 + mt*4 + r
//        (still a packed ushort4 store).
// ---------------------------------------------------------------------------
__global__ __launch_bounds__(256) void qkv_mfma_kernel(
    const unsigned short* __restrict__ xbf,   // [N][512] bf16
    const unsigned short* __restrict__ wtq,   // [24][64][512] bf16
    const float* __restrict__ bq, const float* __restrict__ bk,
    const float* __restrict__ bv,
    unsigned short* __restrict__ q_bf, unsigned short* __restrict__ k_bf,
    unsigned short* __restrict__ vt_bf)
{
    const int zh = blockIdx.y, z = zh >> 3, h = zh & 7;
    const unsigned short* W = wtq + (size_t)zh * HDIM * DIM;
    const float* b = (z == 0 ? bq : z == 1 ? bk : bv) + h * HDIM;
    const int t = threadIdx.x, w = t >> 6, lane = t & 63;
    const int l15 = lane & 15, quad = lane >> 4;
    const int r0 = blockIdx.x * 128 + w * 32;

    f32x4 O[2][4];
    #pragma unroll
    for (int mt = 0; mt < 2; ++mt)
        #pragma unroll
        for (int tn = 0; tn < 4; ++tn) O[mt][tn] = (f32x4){0.f, 0.f, 0.f, 0.f};

    for (int k0 = 0; k0 < DIM; k0 += 64) {
        bf16x8 af[2][2], bf[4][2];
        #pragma unroll
        for (int mt = 0; mt < 2; ++mt)
            #pragma unroll
            for (int kc = 0; kc < 2; ++kc)
                af[mt][kc] = *(const bf16x8*)
                    &xbf[(size_t)(r0 + 16 * mt + l15) * DIM + k0 + quad * 8 + 32 * kc];
        #pragma unroll
        for (int tn = 0; tn < 4; ++tn)
            #pragma unroll
            for (int kc = 0; kc < 2; ++kc)
                bf[tn][kc] = *(const bf16x8*)
                    &W[(size_t)(l15 + 16 * tn) * DIM + k0 + quad * 8 + 32 * kc];
        #pragma unroll
        for (int mt = 0; mt < 2; ++mt)
            #pragma unroll
            for (int tn = 0; tn < 4; ++tn) {
                O[mt][tn] = __builtin_amdgcn_mfma_f32_16x16x32_bf16(
                    af[mt][0], bf[tn][0], O[mt][tn], 0, 0, 0);
                O[mt][tn] = __builtin_amdgcn_mfma_f32_16x16x32_bf16(
                    af[mt][1], bf[tn][1], O[mt][tn], 0, 0, 0);
            }
    }

    if (z < 2) {
        unsigned short* outp = (z == 0 ? q_bf : k_bf) + (size_t)h * NPTS * HDIM;
        const float sc = (z == 0) ? 0.18033688011112042f : 1.0f;  // 0.125*log2e | 1
        #pragma unroll
        for (int mt = 0; mt < 2; ++mt)
            #pragma unroll
            for (int tn = 0; tn < 4; ++tn) {
                int e = l15 + 16 * tn;
                float be = b[e];
                #pragma unroll
                for (int r = 0; r < 4; ++r) {
                    int n = r0 + 16 * mt + quad * 4 + r;
                    outp[(size_t)n * HDIM + e] = f2bf((O[mt][tn][r] + be) * sc);
                }
            }
    } else {
        unsigned short* vt = vt_bf + (size_t)h * HDIM * NPTS;
        #pragma unroll
        for (int mt = 0; mt < 2; ++mt)
            #pragma unroll
            for (int tn = 0; tn < 4; ++tn) {
                int e = l15 + 16 * tn;
                float be = b[e];
                uint2 pk;
                pk.x = pk2bf(O[mt][tn][0] + be, O[mt][tn][1] + be);
                pk.y = pk2bf(O[mt][tn][2] + be, O[mt][tn][3] + be);
                // sigma-permuted position within this 32-row block
                *(uint2*)&vt[(size_t)e * NPTS + r0 + quad * 8 + mt * 4] = pk;
            }
    }
}

// ---------------------------------------------------------------------------
// MFMA flash attention, R8 = R7 transpose trick (register-resident P) with
// R6-quality V loads: vtp stores V^T sigma-permuted per 32-key block, so each
// V A-frag is ONE contiguous 16B load. V loads issue BEFORE the K stage so
// the pre-PV wait is vmcnt(2), leaving the staging in flight. Packed
// v_cvt_pk_bf16_f32 for P/O conversions. Max-free softmax; k-split 2.
// ---------------------------------------------------------------------------
__global__ __launch_bounds__(256) void attn_kernel(
    const unsigned short* __restrict__ qg,   // [H][N][64] bf16, pre-scaled
    const unsigned short* __restrict__ kg,   // [H][N][64] bf16
    const unsigned short* __restrict__ vtg,  // [H][64][N] bf16, sigma-permuted
    unsigned short* __restrict__ opart,      // [2][N][DIM] bf16 unnormalized
    float* __restrict__ lpart)               // [2][H][N] fp32
{
    const int h  = blockIdx.y;
    const int ks = blockIdx.z;
    const int q0 = blockIdx.x * 128;
    const int kbase = ks * (NPTS / 2);
    const unsigned short* Q  = qg  + (size_t)h * NPTS * HDIM;
    const unsigned short* K  = kg  + (size_t)h * NPTS * HDIM;
    const unsigned short* Vt = vtg + (size_t)h * HDIM * NPTS;
    unsigned short* op = opart + (size_t)ks * NPTS * DIM;
    float* lp = lpart + (size_t)(ks * NHEAD + h) * NPTS;

    __shared__ __align__(16) unsigned short Klds[2][64 * 64];  // 16 KB total

    const int t    = threadIdx.x;
    const int w    = t >> 6;
    const int lane = t & 63;
    const int l15  = lane & 15;
    const int quad = lane >> 4;

    const int koff0 = l15 * 64 + (quad ^ (l15 & 7)) * 8;
    const int koff1 = koff0 ^ 32;

    const int srow   = lane >> 3;
    const int schunk = (lane & 7) ^ srow;

    // Q B-frags
    bf16x8 qf[2][2];
    #pragma unroll
    for (int m = 0; m < 2; ++m)
        #pragma unroll
        for (int kc = 0; kc < 2; ++kc)
            qf[m][kc] = *(const bf16x8*)
                &Q[(size_t)(q0 + 32 * w + 16 * m + l15) * HDIM + quad * 8 + 32 * kc];

    // O^T accumulators [te][m]: row=quad*4+r -> e, col=l15 -> qrow
    f32x4 OT[4][2];
    float lsum[2] = {0.f, 0.f};
    #pragma unroll
    for (int te = 0; te < 4; ++te)
        #pragma unroll
        for (int m = 0; m < 2; ++m) OT[te][m] = (f32x4){0.f, 0.f, 0.f, 0.f};

    auto stage = [&](int kt, int buf) {
        #pragma unroll
        for (int i = 0; i < 2; ++i) {
            int rb = 16 * w + 8 * i;
            __builtin_amdgcn_global_load_lds(
                (const GLOBAL_AS void*)&K[(size_t)(kbase + kt + rb + srow) * HDIM
                                          + schunk * 8],
                (LDS_AS void*)&Klds[buf][rb * 64], 16, 0, 0);
        }
    };

    stage(0, 0);
    __syncthreads();
    int buf = 0;

    for (int kt = 0; kt < NPTS / 2; kt += 64) {
        // V A-frags FIRST (single 16B load each, sigma pre-applied in vtp)
        bf16x8 vf[4][2];
        #pragma unroll
        for (int te = 0; te < 4; ++te)
            #pragma unroll
            for (int kb = 0; kb < 2; ++kb)
                vf[te][kb] = *(const bf16x8*)
                    &Vt[(size_t)(16 * te + l15) * NPTS + kbase + kt + kb * 32 + quad * 8];

        // then stage next K tile (younger in vmcnt order -> PV waits vmcnt(2))
        if (kt + 64 < NPTS / 2) stage(kt + 64, buf ^ 1);

        // K A-frags from LDS
        bf16x8 kf[4][2];
        #pragma unroll
        for (int kn = 0; kn < 4; ++kn) {
            kf[kn][0] = *(const bf16x8*)&Klds[buf][1024 * kn + koff0];
            kf[kn][1] = *(const bf16x8*)&Klds[buf][1024 * kn + koff1];
        }

        // S^T = K Q^T : st[kn][m], row=key(quad*4+r), col=qrow(l15)
        f32x4 st[4][2];
        #pragma unroll
        for (int kn = 0; kn < 4; ++kn)
            #pragma unroll
            for (int m = 0; m < 2; ++m) st[kn][m] = (f32x4){0.f, 0.f, 0.f, 0.f};
        #pragma unroll
        for (int kn = 0; kn < 4; ++kn)
            #pragma unroll
            for (int m = 0; m < 2; ++m) {
                st[kn][m] = __builtin_amdgcn_mfma_f32_16x16x32_bf16(
                    kf[kn][0], qf[m][0], st[kn][m], 0, 0, 0);
                st[kn][m] = __builtin_amdgcn_mfma_f32_16x16x32_bf16(
                    kf[kn][1], qf[m][1], st[kn][m], 0, 0, 0);
            }

        // max-free softmax in registers: pt = bf16 exp2(S^T), packed cvt
        bf16x8 pt[2][2];
        #pragma unroll
        for (int kb = 0; kb < 2; ++kb)
            #pragma unroll
            for (int m = 0; m < 2; ++m) {
                float a0 = EXP2F(st[2 * kb + 0][m][0]);
                float a1 = EXP2F(st[2 * kb + 0][m][1]);
                float a2 = EXP2F(st[2 * kb + 0][m][2]);
                float a3 = EXP2F(st[2 * kb + 0][m][3]);
                float b0 = EXP2F(st[2 * kb + 1][m][0]);
                float b1 = EXP2F(st[2 * kb + 1][m][1]);
                float b2 = EXP2F(st[2 * kb + 1][m][2]);
                float b3 = EXP2F(st[2 * kb + 1][m][3]);
                lsum[m] += ((a0 + a1) + (a2 + a3)) + ((b0 + b1) + (b2 + b3));
                union { uint4 u; bf16x8 v; } uu;
                uu.u.x = pk2bf(a0, a1);
                uu.u.y = pk2bf(a2, a3);
                uu.u.z = pk2bf(b0, b1);
                uu.u.w = pk2bf(b2, b3);
                pt[kb][m] = uu.v;
            }

        // O^T += V^T P^T  (pure register path)
        #pragma unroll
        for (int te = 0; te < 4; ++te)
            #pragma unroll
            for (int m = 0; m < 2; ++m) {
                OT[te][m] = __builtin_amdgcn_mfma_f32_16x16x32_bf16(
                    vf[te][0], pt[0][m], OT[te][m], 0, 0, 0);
                OT[te][m] = __builtin_amdgcn_mfma_f32_16x16x32_bf16(
                    vf[te][1], pt[1][m], OT[te][m], 0, 0, 0);
            }

        __syncthreads();   // Klds[buf] reads done; next stage visible
        buf ^= 1;
    }

    // epilogue: l reduced across quads; write unnormalized O^T packed
    #pragma unroll
    for (int m = 0; m < 2; ++m) {
        float l = lsum[m];
        l += __shfl_xor(l, 16);
        l += __shfl_xor(l, 32);
        int n = q0 + 32 * w + 16 * m + l15;
        if (quad == 0) lp[n] = l;
        #pragma unroll
        for (int te = 0; te < 4; ++te) {
            uint2 pk;
            pk.x = pk2bf(OT[te][m][0], OT[te][m][1]);
            pk.y = pk2bf(OT[te][m][2], OT[te][m][3]);
            *(uint2*)&op[(size_t)n * DIM + h * HDIM + 16 * te + quad * 4] = pk;
        }
    }
}

// ---------------------------------------------------------------------------
// Merge k-split partials: op0 <- bf16((op0 + op1) / (l0 + l1))  in place.
// ---------------------------------------------------------------------------
__global__ __launch_bounds__(256) void reduce_kernel(
    unsigned short* __restrict__ op0, const unsigned short* __restrict__ op1,
    const float* __restrict__ l0, const float* __restrict__ l1)
{
    int gid = blockIdx.x * 256 + threadIdx.x;   // over N*DIM/4
    int n  = gid >> 7;
    int c4 = gid & 127;
    int h  = c4 >> 4;
    float inv = 1.0f / (l0[h * NPTS + n] + l1[h * NPTS + n]);
    ushort4 a = *(const ushort4*)&op0[(size_t)gid * 4];
    ushort4 b = *(const ushort4*)&op1[(size_t)gid * 4];
    uint2 o;
    o.x = pk2bf((bf2f(a.x) + bf2f(b.x)) * inv, (bf2f(a.y) + bf2f(b.y)) * inv);
    o.y = pk2bf((bf2f(a.z) + bf2f(b.z)) * inv, (bf2f(a.w) + bf2f(b.w)) * inv);
    *(uint2*)&op0[(size_t)gid * 4] = o;
}

// ---------------------------------------------------------------------------
// Output projection, bf16 MFMA, direct-global frags.
// ---------------------------------------------------------------------------
__global__ __launch_bounds__(256) void out_mfma_kernel(
    const unsigned short* __restrict__ cc,    // [N][512] bf16 normalized heads
    const unsigned short* __restrict__ wot,   // [512][512] bf16 [e_out][k]
    const float* __restrict__ bo, const float* __restrict__ x,
    float* __restrict__ outp)
{
    const int t = threadIdx.x, w = t >> 6, lane = t & 63;
    const int l15 = lane & 15, quad = lane >> 4;
    const int r0 = blockIdx.x * 128 + w * 32;
    const int c0 = blockIdx.y * 64;

    f32x4 O[2][4];
    #pragma unroll
    for (int mt = 0; mt < 2; ++mt)
        #pragma unroll
        for (int tn = 0; tn < 4; ++tn) O[mt][tn] = (f32x4){0.f, 0.f, 0.f, 0.f};

    for (int k0 = 0; k0 < DIM; k0 += 64) {
        bf16x8 af[2][2], bf[4][2];
        #pragma unroll
        for (int mt = 0; mt < 2; ++mt)
            #pragma unroll
            for (int kc = 0; kc < 2; ++kc)
                af[mt][kc] = *(const bf16x8*)
                    &cc[(size_t)(r0 + 16 * mt + l15) * DIM + k0 + quad * 8 + 32 * kc];
        #pragma unroll
        for (int tn = 0; tn < 4; ++tn)
            #pragma unroll
            for (int kc = 0; kc < 2; ++kc)
                bf[tn][kc] = *(const bf16x8*)
                    &wot[(size_t)(c0 + l15 + 16 * tn) * DIM + k0 + quad * 8 + 32 * kc];
        #pragma unroll
        for (int mt = 0; mt < 2; ++mt)
            #pragma unroll
            for (int tn = 0; tn < 4; ++tn) {
                O[mt][tn] = __builtin_amdgcn_mfma_f32_16x16x32_bf16(
                    af[mt][0], bf[tn][0], O[mt][tn], 0, 0, 0);
                O[mt][tn] = __builtin_amdgcn_mfma_f32_16x16x32_bf16(
                    af[mt][1], bf[tn][1], O[mt][tn], 0, 0, 0);
            }
    }

    #pragma unroll
    for (int mt = 0; mt < 2; ++mt)
        #pragma unroll
        for (int tn = 0; tn < 4; ++tn) {
            int e = c0 + l15 + 16 * tn;
            float be = bo[e];
            #pragma unroll
            for (int r = 0; r < 4; ++r) {
                int n = r0 + 16 * mt + quad * 4 + r;
                outp[(size_t)n * DIM + e] = O[mt][tn][r] + be + x[(size_t)n * DIM + e];
            }
        }
}

extern "C" void kernel_launch(void* const* d_in, const int* in_sizes, int n_in,
                              void* d_out, int out_size, void* d_ws, size_t ws_size,
                              hipStream_t stream) {
    const float* x  = (const float*)d_in[0];
    const float* Wq = (const float*)d_in[1];
    const float* bq = (const float*)d_in[2];
    const float* Wk = (const float*)d_in[3];
    const float* bk = (const float*)d_in[4];
    const float* Wv = (const float*)d_in[5];
    const float* bv = (const float*)d_in[6];
    const float* Wo = (const float*)d_in[7];
    const float* bo = (const float*)d_in[8];
    float* out = (float*)d_out;

    const size_t per = (size_t)NHEAD * NPTS * HDIM;            // 4M elems
    unsigned short* xbf   = (unsigned short*)d_ws;             //  8 MB
    unsigned short* wtq   = xbf + (size_t)NPTS * DIM;          //  1.5 MB
    unsigned short* wot   = wtq + (size_t)24 * HDIM * DIM;     //  0.5 MB
    unsigned short* q_bf  = wot + (size_t)DIM * DIM;           //  8 MB
    unsigned short* k_bf  = q_bf + per;                        //  8 MB
    unsigned short* vt_bf = k_bf + per;                        //  8 MB
    unsigned short* op0   = vt_bf + per;                       //  8 MB
    unsigned short* op1   = op0 + (size_t)NPTS * DIM;          //  8 MB
    float*          lpart = (float*)(op1 + (size_t)NPTS * DIM); // 512 KB
    // total ws: ~50.5 MB

    cvt_x_kernel<<<dim3(NPTS * DIM / 8 / 256), 256, 0, stream>>>(x, xbf);
    tr_w_kernel<<<dim3(8, 1, 24), 256, 0, stream>>>(Wq, Wk, Wv, wtq);
    tr_wo_kernel<<<dim3(8, 8), 256, 0, stream>>>(Wo, wot);
    qkv_mfma_kernel<<<dim3(NPTS / 128, 24), 256, 0, stream>>>(
        xbf, wtq, bq, bk, bv, q_bf, k_bf, vt_bf);
    attn_kernel<<<dim3(NPTS / 128, NHEAD, 2), 256, 0, stream>>>(
        q_bf, k_bf, vt_bf, op0, lpart);
    reduce_kernel<<<dim3(NPTS * DIM / 4 / 256), 256, 0, stream>>>(
        op0, op1, lpart, lpart + (size_t)NHEAD * NPTS);
    out_mfma_kernel<<<dim3(NPTS / 128, DIM / 64), 256, 0, stream>>>(
        op0, wot, bo, x, out);
}

// Round 9
// 350.577 us; speedup vs baseline: 1.9034x; 1.2793x over previous
//
#include <hip/hip_runtime.h>
#include <hip/hip_bf16.h>

#define NPTS 8192
#define DIM  512
#define NHEAD 8
#define HDIM 64

typedef short bf16x8 __attribute__((ext_vector_type(8)));   // 8 bf16 = 4 VGPRs
typedef float f32x4  __attribute__((ext_vector_type(4)));   // MFMA C/D

#define GLOBAL_AS __attribute__((address_space(1)))
#define LDS_AS    __attribute__((address_space(3)))

#if __has_builtin(__builtin_amdgcn_exp2f)
#define EXP2F(x) __builtin_amdgcn_exp2f(x)
#else
#define EXP2F(x) __expf((x) * 0.6931471805599453f)
#endif

// fp32 -> bf16 round-nearest-even (scalar)
__device__ __forceinline__ unsigned short f2bf(float f) {
    union { float f; unsigned int u; } v; v.f = f;
    unsigned int r = v.u + 0x7FFFu + ((v.u >> 16) & 1u);
    return (unsigned short)(r >> 16);
}
__device__ __forceinline__ float bf2f(unsigned short u) {
    union { unsigned int i; float f; } v; v.i = ((unsigned int)u) << 16;
    return v.f;
}
// packed 2x f32 -> bf16 pair (v_cvt_pk_bf16_f32 on gfx950)
__device__ __forceinline__ unsigned int pk2bf(float a, float b) {
    __hip_bfloat162 h = __float22bfloat162_rn(float2{a, b});
    union { __hip_bfloat162 h; unsigned int u; } v; v.h = h;
    return v.u;
}

// ---------------------------------------------------------------------------
// Prep 1: x fp32 -> bf16
// ---------------------------------------------------------------------------
__global__ __launch_bounds__(256) void cvt_x_kernel(
    const float* __restrict__ in, unsigned short* __restrict__ outp)
{
    int gid = blockIdx.x * 256 + threadIdx.x;   // over N*DIM/8
    float4 a = ((const float4*)in)[gid * 2];
    float4 b = ((const float4*)in)[gid * 2 + 1];
    uint4 u;
    u.x = pk2bf(a.x, a.y); u.y = pk2bf(a.z, a.w);
    u.z = pk2bf(b.x, b.y); u.w = pk2bf(b.z, b.w);
    ((uint4*)outp)[gid] = u;
}

// ---------------------------------------------------------------------------
// Prep 2: Wq/Wk/Wv [h][512][64] fp32 -> wtq [zh][64][512] bf16 (transposed)
// ---------------------------------------------------------------------------
__global__ __launch_bounds__(256) void tr_w_kernel(
    const float* __restrict__ Wq, const float* __restrict__ Wk,
    const float* __restrict__ Wv, unsigned short* __restrict__ wtq)
{
    int zh = blockIdx.z, z = zh >> 3, h = zh & 7;
    const float* src = (z == 0 ? Wq : z == 1 ? Wk : Wv) + (size_t)h * DIM * HDIM;
    unsigned short* dst = wtq + (size_t)zh * HDIM * DIM;
    int k0 = blockIdx.x * 64;
    __shared__ float tile[64][65];
    int t = threadIdx.x, c = t & 63, r = t >> 6;
    #pragma unroll
    for (int i = 0; i < 16; ++i)
        tile[r + 4 * i][c] = src[(size_t)(k0 + r + 4 * i) * HDIM + c];
    __syncthreads();
    #pragma unroll
    for (int i = 0; i < 16; ++i)
        dst[(size_t)(r + 4 * i) * DIM + k0 + c] = f2bf(tile[c][r + 4 * i]);
}

// ---------------------------------------------------------------------------
// Prep 3: Wo [512][512] fp32 -> wot [512][512] bf16 transposed ([e_out][k])
// ---------------------------------------------------------------------------
__global__ __launch_bounds__(256) void tr_wo_kernel(
    const float* __restrict__ Wo, unsigned short* __restrict__ wot)
{
    int k0 = blockIdx.x * 64, e0 = blockIdx.y * 64;
    __shared__ float tile[64][65];
    int t = threadIdx.x, c = t & 63, r = t >> 6;
    #pragma unroll
    for (int i = 0; i < 16; ++i)
        tile[r + 4 * i][c] = Wo[(size_t)(k0 + r + 4 * i) * DIM + e0 + c];
    __syncthreads();
    #pragma unroll
    for (int i = 0; i < 16; ++i)
        wot[(size_t)(e0 + r + 4 * i) * DIM + k0 + c] = f2bf(tile[c][r + 4 * i]);
}

// ---------------------------------------------------------------------------
// QKV projection, bf16 MFMA, direct-global frags.
//   z=0: q_bf[h][n][e]  (scale*log2e folded)   z=1: k_bf[h][n][e]
//   z=2: vtp[h][e][pi(n)] = V^T with the PV sigma-permutation pre-applied
//        within each 32-key block (pos = 8*quad + 4*mt + r holds
//        key = 16*mt + 4*quad + r) -- matches P^T's B-frag key order.
// ---------------------------------------------------------------------------
__global__ __launch_bounds__(256) void qkv_mfma_kernel(
    const unsigned short* __restrict__ xbf,   // [N][512] bf16
    const unsigned short* __restrict__ wtq,   // [24][64][512] bf16
    const float* __restrict__ bq, const float* __restrict__ bk,
    const float* __restrict__ bv,
    unsigned short* __restrict__ q_bf, unsigned short* __restrict__ k_bf,
    unsigned short* __restrict__ vt_bf)
{
    const int zh = blockIdx.y, z = zh >> 3, h = zh & 7;
    const unsigned short* W = wtq + (size_t)zh * HDIM * DIM;
    const float* b = (z == 0 ? bq : z == 1 ? bk : bv) + h * HDIM;
    const int t = threadIdx.x, w = t >> 6, lane = t & 63;
    const int l15 = lane & 15, quad = lane >> 4;
    const int r0 = blockIdx.x * 128 + w * 32;

    f32x4 O[2][4];
    #pragma unroll
    for (int mt = 0; mt < 2; ++mt)
        #pragma unroll
        for (int tn = 0; tn < 4; ++tn) O[mt][tn] = (f32x4){0.f, 0.f, 0.f, 0.f};

    for (int k0 = 0; k0 < DIM; k0 += 64) {
        bf16x8 af[2][2], bf[4][2];
        #pragma unroll
        for (int mt = 0; mt < 2; ++mt)
            #pragma unroll
            for (int kc = 0; kc < 2; ++kc)
                af[mt][kc] = *(const bf16x8*)
                    &xbf[(size_t)(r0 + 16 * mt + l15) * DIM + k0 + quad * 8 + 32 * kc];
        #pragma unroll
        for (int tn = 0; tn < 4; ++tn)
            #pragma unroll
            for (int kc = 0; kc < 2; ++kc)
                bf[tn][kc] = *(const bf16x8*)
                    &W[(size_t)(l15 + 16 * tn) * DIM + k0 + quad * 8 + 32 * kc];
        #pragma unroll
        for (int mt = 0; mt < 2; ++mt)
            #pragma unroll
            for (int tn = 0; tn < 4; ++tn) {
                O[mt][tn] = __builtin_amdgcn_mfma_f32_16x16x32_bf16(
                    af[mt][0], bf[tn][0], O[mt][tn], 0, 0, 0);
                O[mt][tn] = __builtin_amdgcn_mfma_f32_16x16x32_bf16(
                    af[mt][1], bf[tn][1], O[mt][tn], 0, 0, 0);
            }
    }

    if (z < 2) {
        unsigned short* outp = (z == 0 ? q_bf : k_bf) + (size_t)h * NPTS * HDIM;
        const float sc = (z == 0) ? 0.18033688011112042f : 1.0f;  // 0.125*log2e | 1
        #pragma unroll
        for (int mt = 0; mt < 2; ++mt)
            #pragma unroll
            for (int tn = 0; tn < 4; ++tn) {
                int e = l15 + 16 * tn;
                float be = b[e];
                #pragma unroll
                for (int r = 0; r < 4; ++r) {
                    int n = r0 + 16 * mt + quad * 4 + r;
                    outp[(size_t)n * HDIM + e] = f2bf((O[mt][tn][r] + be) * sc);
                }
            }
    } else {
        unsigned short* vt = vt_bf + (size_t)h * HDIM * NPTS;
        #pragma unroll
        for (int mt = 0; mt < 2; ++mt)
            #pragma unroll
            for (int tn = 0; tn < 4; ++tn) {
                int e = l15 + 16 * tn;
                float be = b[e];
                uint2 pk;
                pk.x = pk2bf(O[mt][tn][0] + be, O[mt][tn][1] + be);
                pk.y = pk2bf(O[mt][tn][2] + be, O[mt][tn][3] + be);
                // sigma-permuted position within this 32-row block
                *(uint2*)&vt[(size_t)e * NPTS + r0 + quad * 8 + mt * 4] = pk;
            }
    }
}

// ---------------------------------------------------------------------------
// MFMA flash attention, R9: register-resident P (R8 transpose trick) +
// BOTH K and V staged in LDS (V was the L1-line hog: direct V frag loads
// cost 512 lines/block-iter vs 128 staged; L1 ~1 line/cyc was the ceiling).
// V staging mirrors K exactly: same row-wise DMA, same XOR chunk swizzle,
// same conflict-free koff read pattern (vtp rows are e, cols sigma-permuted
// keys). Double-buffered, one barrier/iter; max-free softmax; k-split 2.
// ---------------------------------------------------------------------------
__global__ __launch_bounds__(256) void attn_kernel(
    const unsigned short* __restrict__ qg,   // [H][N][64] bf16, pre-scaled
    const unsigned short* __restrict__ kg,   // [H][N][64] bf16
    const unsigned short* __restrict__ vtg,  // [H][64][N] bf16, sigma-permuted
    unsigned short* __restrict__ opart,      // [2][N][DIM] bf16 unnormalized
    float* __restrict__ lpart)               // [2][H][N] fp32
{
    const int h  = blockIdx.y;
    const int ks = blockIdx.z;
    const int q0 = blockIdx.x * 128;
    const int kbase = ks * (NPTS / 2);
    const unsigned short* Q  = qg  + (size_t)h * NPTS * HDIM;
    const unsigned short* K  = kg  + (size_t)h * NPTS * HDIM;
    const unsigned short* Vt = vtg + (size_t)h * HDIM * NPTS;
    unsigned short* op = opart + (size_t)ks * NPTS * DIM;
    float* lp = lpart + (size_t)(ks * NHEAD + h) * NPTS;

    __shared__ __align__(16) unsigned short Klds[2][64 * 64];  // 16 KB
    __shared__ __align__(16) unsigned short Vlds[2][64 * 64];  // 16 KB

    const int t    = threadIdx.x;
    const int w    = t >> 6;
    const int lane = t & 63;
    const int l15  = lane & 15;
    const int quad = lane >> 4;

    const int koff0 = l15 * 64 + (quad ^ (l15 & 7)) * 8;
    const int koff1 = koff0 ^ 32;

    const int srow   = lane >> 3;
    const int schunk = (lane & 7) ^ srow;

    // Q B-frags
    bf16x8 qf[2][2];
    #pragma unroll
    for (int m = 0; m < 2; ++m)
        #pragma unroll
        for (int kc = 0; kc < 2; ++kc)
            qf[m][kc] = *(const bf16x8*)
                &Q[(size_t)(q0 + 32 * w + 16 * m + l15) * HDIM + quad * 8 + 32 * kc];

    // O^T accumulators [te][m]: row=quad*4+r -> e, col=l15 -> qrow
    f32x4 OT[4][2];
    float lsum[2] = {0.f, 0.f};
    #pragma unroll
    for (int te = 0; te < 4; ++te)
        #pragma unroll
        for (int m = 0; m < 2; ++m) OT[te][m] = (f32x4){0.f, 0.f, 0.f, 0.f};

    // stage one 64-key K tile + matching V tile; 4 waves x 2 issues each
    auto stage = [&](int kt, int buf) {
        #pragma unroll
        for (int i = 0; i < 2; ++i) {
            int rb = 16 * w + 8 * i;
            __builtin_amdgcn_global_load_lds(
                (const GLOBAL_AS void*)&K[(size_t)(kbase + kt + rb + srow) * HDIM
                                          + schunk * 8],
                (LDS_AS void*)&Klds[buf][rb * 64], 16, 0, 0);
            __builtin_amdgcn_global_load_lds(
                (const GLOBAL_AS void*)&Vt[(size_t)(rb + srow) * NPTS
                                           + kbase + kt + schunk * 8],
                (LDS_AS void*)&Vlds[buf][rb * 64], 16, 0, 0);
        }
    };

    stage(0, 0);
    __syncthreads();
    int buf = 0;

    for (int kt = 0; kt < NPTS / 2; kt += 64) {
        // issue next stage first: a full body of latency cover before the
        // barrier's vmcnt(0) drain
        if (kt + 64 < NPTS / 2) stage(kt + 64, buf ^ 1);

        // K A-frags from LDS
        bf16x8 kf[4][2];
        #pragma unroll
        for (int kn = 0; kn < 4; ++kn) {
            kf[kn][0] = *(const bf16x8*)&Klds[buf][1024 * kn + koff0];
            kf[kn][1] = *(const bf16x8*)&Klds[buf][1024 * kn + koff1];
        }

        // S^T = K Q^T : st[kn][m], row=key(quad*4+r), col=qrow(l15)
        f32x4 st[4][2];
        #pragma unroll
        for (int kn = 0; kn < 4; ++kn)
            #pragma unroll
            for (int m = 0; m < 2; ++m) st[kn][m] = (f32x4){0.f, 0.f, 0.f, 0.f};
        #pragma unroll
        for (int kn = 0; kn < 4; ++kn)
            #pragma unroll
            for (int m = 0; m < 2; ++m) {
                st[kn][m] = __builtin_amdgcn_mfma_f32_16x16x32_bf16(
                    kf[kn][0], qf[m][0], st[kn][m], 0, 0, 0);
                st[kn][m] = __builtin_amdgcn_mfma_f32_16x16x32_bf16(
                    kf[kn][1], qf[m][1], st[kn][m], 0, 0, 0);
            }

        // V A-frags from LDS (identical pattern to kf; kf regs dead by now)
        bf16x8 vf[4][2];
        #pragma unroll
        for (int te = 0; te < 4; ++te) {
            vf[te][0] = *(const bf16x8*)&Vlds[buf][1024 * te + koff0];
            vf[te][1] = *(const bf16x8*)&Vlds[buf][1024 * te + koff1];
        }

        // max-free softmax in registers: pt = bf16 exp2(S^T), packed cvt
        bf16x8 pt[2][2];
        #pragma unroll
        for (int kb = 0; kb < 2; ++kb)
            #pragma unroll
            for (int m = 0; m < 2; ++m) {
                float a0 = EXP2F(st[2 * kb + 0][m][0]);
                float a1 = EXP2F(st[2 * kb + 0][m][1]);
                float a2 = EXP2F(st[2 * kb + 0][m][2]);
                float a3 = EXP2F(st[2 * kb + 0][m][3]);
                float b0 = EXP2F(st[2 * kb + 1][m][0]);
                float b1 = EXP2F(st[2 * kb + 1][m][1]);
                float b2 = EXP2F(st[2 * kb + 1][m][2]);
                float b3 = EXP2F(st[2 * kb + 1][m][3]);
                lsum[m] += ((a0 + a1) + (a2 + a3)) + ((b0 + b1) + (b2 + b3));
                union { uint4 u; bf16x8 v; } uu;
                uu.u.x = pk2bf(a0, a1);
                uu.u.y = pk2bf(a2, a3);
                uu.u.z = pk2bf(b0, b1);
                uu.u.w = pk2bf(b2, b3);
                pt[kb][m] = uu.v;
            }

        // O^T += V^T P^T  (pure register path)
        #pragma unroll
        for (int te = 0; te < 4; ++te)
            #pragma unroll
            for (int m = 0; m < 2; ++m) {
                OT[te][m] = __builtin_amdgcn_mfma_f32_16x16x32_bf16(
                    vf[te][0], pt[0][m], OT[te][m], 0, 0, 0);
                OT[te][m] = __builtin_amdgcn_mfma_f32_16x16x32_bf16(
                    vf[te][1], pt[1][m], OT[te][m], 0, 0, 0);
            }

        __syncthreads();   // Klds/Vlds[buf] reads done; next stage visible
        buf ^= 1;
    }

    // epilogue: l reduced across quads; write unnormalized O^T packed
    #pragma unroll
    for (int m = 0; m < 2; ++m) {
        float l = lsum[m];
        l += __shfl_xor(l, 16);
        l += __shfl_xor(l, 32);
        int n = q0 + 32 * w + 16 * m + l15;
        if (quad == 0) lp[n] = l;
        #pragma unroll
        for (int te = 0; te < 4; ++te) {
            uint2 pk;
            pk.x = pk2bf(OT[te][m][0], OT[te][m][1]);
            pk.y = pk2bf(OT[te][m][2], OT[te][m][3]);
            *(uint2*)&op[(size_t)n * DIM + h * HDIM + 16 * te + quad * 4] = pk;
        }
    }
}

// ---------------------------------------------------------------------------
// Merge k-split partials: op0 <- bf16((op0 + op1) / (l0 + l1))  in place.
// ---------------------------------------------------------------------------
__global__ __launch_bounds__(256) void reduce_kernel(
    unsigned short* __restrict__ op0, const unsigned short* __restrict__ op1,
    const float* __restrict__ l0, const float* __restrict__ l1)
{
    int gid = blockIdx.x * 256 + threadIdx.x;   // over N*DIM/4
    int n  = gid >> 7;
    int c4 = gid & 127;
    int h  = c4 >> 4;
    float inv = 1.0f / (l0[h * NPTS + n] + l1[h * NPTS + n]);
    ushort4 a = *(const ushort4*)&op0[(size_t)gid * 4];
    ushort4 b = *(const ushort4*)&op1[(size_t)gid * 4];
    uint2 o;
    o.x = pk2bf((bf2f(a.x) + bf2f(b.x)) * inv, (bf2f(a.y) + bf2f(b.y)) * inv);
    o.y = pk2bf((bf2f(a.z) + bf2f(b.z)) * inv, (bf2f(a.w) + bf2f(b.w)) * inv);
    *(uint2*)&op0[(size_t)gid * 4] = o;
}

// ---------------------------------------------------------------------------
// Output projection, bf16 MFMA, direct-global frags.
// ---------------------------------------------------------------------------
__global__ __launch_bounds__(256) void out_mfma_kernel(
    const unsigned short* __restrict__ cc,    // [N][512] bf16 normalized heads
    const unsigned short* __restrict__ wot,   // [512][512] bf16 [e_out][k]
    const float* __restrict__ bo, const float* __restrict__ x,
    float* __restrict__ outp)
{
    const int t = threadIdx.x, w = t >> 6, lane = t & 63;
    const int l15 = lane & 15, quad = lane >> 4;
    const int r0 = blockIdx.x * 128 + w * 32;
    const int c0 = blockIdx.y * 64;

    f32x4 O[2][4];
    #pragma unroll
    for (int mt = 0; mt < 2; ++mt)
        #pragma unroll
        for (int tn = 0; tn < 4; ++tn) O[mt][tn] = (f32x4){0.f, 0.f, 0.f, 0.f};

    for (int k0 = 0; k0 < DIM; k0 += 64) {
        bf16x8 af[2][2], bf[4][2];
        #pragma unroll
        for (int mt = 0; mt < 2; ++mt)
            #pragma unroll
            for (int kc = 0; kc < 2; ++kc)
                af[mt][kc] = *(const bf16x8*)
                    &cc[(size_t)(r0 + 16 * mt + l15) * DIM + k0 + quad * 8 + 32 * kc];
        #pragma unroll
        for (int tn = 0; tn < 4; ++tn)
            #pragma unroll
            for (int kc = 0; kc < 2; ++kc)
                bf[tn][kc] = *(const bf16x8*)
                    &wot[(size_t)(c0 + l15 + 16 * tn) * DIM + k0 + quad * 8 + 32 * kc];
        #pragma unroll
        for (int mt = 0; mt < 2; ++mt)
            #pragma unroll
            for (int tn = 0; tn < 4; ++tn) {
                O[mt][tn] = __builtin_amdgcn_mfma_f32_16x16x32_bf16(
                    af[mt][0], bf[tn][0], O[mt][tn], 0, 0, 0);
                O[mt][tn] = __builtin_amdgcn_mfma_f32_16x16x32_bf16(
                    af[mt][1], bf[tn][1], O[mt][tn], 0, 0, 0);
            }
    }

    #pragma unroll
    for (int mt = 0; mt < 2; ++mt)
        #pragma unroll
        for (int tn = 0; tn < 4; ++tn) {
            int e = c0 + l15 + 16 * tn;
            float be = bo[e];
            #pragma unroll
            for (int r = 0; r < 4; ++r) {
                int n = r0 + 16 * mt + quad * 4 + r;
                outp[(size_t)n * DIM + e] = O[mt][tn][r] + be + x[(size_t)n * DIM + e];
            }
        }
}

extern "C" void kernel_launch(void* const* d_in, const int* in_sizes, int n_in,
                              void* d_out, int out_size, void* d_ws, size_t ws_size,
                              hipStream_t stream) {
    const float* x  = (const float*)d_in[0];
    const float* Wq = (const float*)d_in[1];
    const float* bq = (const float*)d_in[2];
    const float* Wk = (const float*)d_in[3];
    const float* bk = (const float*)d_in[4];
    const float* Wv = (const float*)d_in[5];
    const float* bv = (const float*)d_in[6];
    const float* Wo = (const float*)d_in[7];
    const float* bo = (const float*)d_in[8];
    float* out = (float*)d_out;

    const size_t per = (size_t)NHEAD * NPTS * HDIM;            // 4M elems
    unsigned short* xbf   = (unsigned short*)d_ws;             //  8 MB
    unsigned short* wtq   = xbf + (size_t)NPTS * DIM;          //  1.5 MB
    unsigned short* wot   = wtq + (size_t)24 * HDIM * DIM;     //  0.5 MB
    unsigned short* q_bf  = wot + (size_t)DIM * DIM;           //  8 MB
    unsigned short* k_bf  = q_bf + per;                        //  8 MB
    unsigned short* vt_bf = k_bf + per;                        //  8 MB
    unsigned short* op0   = vt_bf + per;                       //  8 MB
    unsigned short* op1   = op0 + (size_t)NPTS * DIM;          //  8 MB
    float*          lpart = (float*)(op1 + (size_t)NPTS * DIM); // 512 KB
    // total ws: ~50.5 MB

    cvt_x_kernel<<<dim3(NPTS * DIM / 8 / 256), 256, 0, stream>>>(x, xbf);
    tr_w_kernel<<<dim3(8, 1, 24), 256, 0, stream>>>(Wq, Wk, Wv, wtq);
    tr_wo_kernel<<<dim3(8, 8), 256, 0, stream>>>(Wo, wot);
    qkv_mfma_kernel<<<dim3(NPTS / 128, 24), 256, 0, stream>>>(
        xbf, wtq, bq, bk, bv, q_bf, k_bf, vt_bf);
    attn_kernel<<<dim3(NPTS / 128, NHEAD, 2), 256, 0, stream>>>(
        q_bf, k_bf, vt_bf, op0, lpart);
    reduce_kernel<<<dim3(NPTS * DIM / 4 / 256), 256, 0, stream>>>(
        op0, op1, lpart, lpart + (size_t)NHEAD * NPTS);
    out_mfma_kernel<<<dim3(NPTS / 128, DIM / 64), 256, 0, stream>>>(
        op0, wot, bo, x, out);
}